// Round 3
// baseline (510.432 us; speedup 1.0000x reference)
//
#include <hip/hip_runtime.h>
#include <math.h>

#define NDIM 64

// K0: histogram of destination nodes vj.
__global__ void __launch_bounds__(256)
k0_hist(const int* __restrict__ edges, int* __restrict__ hist, int n_edges) {
    const int e = blockIdx.x * 256 + threadIdx.x;
    if (e < n_edges) atomicAdd(&hist[edges[e * 8 + 2]], 1);
}

// ---- exclusive scan over hist (n <= 256*256 entries) ----
__global__ void __launch_bounds__(256)
scan_blocks(int* __restrict__ data, int* __restrict__ bsum, int n) {
    __shared__ int sm[256];
    const int t = threadIdx.x;
    const int i = blockIdx.x * 256 + t;
    int v = (i < n) ? data[i] : 0;
    sm[t] = v;
    __syncthreads();
    int x = v;
    #pragma unroll
    for (int off = 1; off < 256; off <<= 1) {
        int add = (t >= off) ? sm[t - off] : 0;
        __syncthreads();
        x += add; sm[t] = x;
        __syncthreads();
    }
    if (i < n) data[i] = x - v;
    if (t == 255) bsum[blockIdx.x] = x;
}

__global__ void __launch_bounds__(256)
scan_top(int* __restrict__ bsum, int nb) {
    __shared__ int sm[256];
    const int t = threadIdx.x;
    int v = (t < nb) ? bsum[t] : 0;
    sm[t] = v;
    __syncthreads();
    int x = v;
    #pragma unroll
    for (int off = 1; off < 256; off <<= 1) {
        int add = (t >= off) ? sm[t - off] : 0;
        __syncthreads();
        x += add; sm[t] = x;
        __syncthreads();
    }
    if (t < nb) bsum[t] = x - v;
}

__global__ void __launch_bounds__(256)
scan_add(int* __restrict__ data, const int* __restrict__ bsum, int n, int total) {
    const int i = blockIdx.x * 256 + threadIdx.x;
    if (i < n) data[i] += bsum[blockIdx.x];
    else if (i == n) data[i] = total;
}

// K1: 4 lanes per edge (16 edges per wave). Computes ex=exp(logit),
// accumulates denom[vi] atomically, scatters (vi, ex) to vj-sorted slot.
#define DIMS4(COMP)                                                          \
    { const float pa = fmaxf(a.COMP, 0.f), na = fmaxf(-a.COMP, 0.f);         \
      const float pb = fmaxf(b.COMP, 0.f), nb = fmaxf(-b.COMP, 0.f);         \
      c += pa * W0[q].COMP + pb * W1[q].COMP + pa * pb * W2[q].COMP          \
         - na * W3[q].COMP - nb * W4[q].COMP - na * nb * W5[q].COMP; }

__global__ void __launch_bounds__(256)
k1_logits(const int* __restrict__ edges,
          const float* __restrict__ h,
          const float* __restrict__ pw,
          const float* __restrict__ nw,
          const int* __restrict__ offs,
          int* __restrict__ cursor,
          float* __restrict__ denom,
          int2* __restrict__ rec,
          int n_edges) {
    const int lane = threadIdx.x & 63;
    const int sub  = lane & 3;        // which 16-dim slice
    const int grp  = lane >> 2;       // which edge in the 16-edge tile
    const int wib  = threadIdx.x >> 6;
    const int wpb  = blockDim.x >> 6;
    const int nwaves = gridDim.x * wpb;
    const int wid = blockIdx.x * wpb + wib;

    const float4* pw4 = (const float4*)pw;
    const float4* nw4 = (const float4*)nw;
    float4 W0[4], W1[4], W2[4], W3[4], W4[4], W5[4];
    #pragma unroll
    for (int q = 0; q < 4; ++q) {
        W0[q] = pw4[     sub * 4 + q];
        W1[q] = pw4[16 + sub * 4 + q];
        W2[q] = pw4[32 + sub * 4 + q];
        W3[q] = nw4[     sub * 4 + q];
        W4[q] = nw4[16 + sub * 4 + q];
        W5[q] = nw4[32 + sub * 4 + q];
    }

    const int ntiles = (n_edges + 15) >> 4;
    for (int t = wid; t < ntiles; t += nwaves) {
        const int e  = t * 16 + grp;
        const int ee = min(e, n_edges - 1);
        const int vi = edges[ee * 8 + 1];
        const int vj = edges[ee * 8 + 2];
        const float4* hi4 = (const float4*)(h + (size_t)vi * NDIM + sub * 16);
        const float4* hj4 = (const float4*)(h + (size_t)vj * NDIM + sub * 16);
        float c = 0.f;
        #pragma unroll
        for (int q = 0; q < 4; ++q) {
            const float4 a = hi4[q];
            const float4 b = hj4[q];
            DIMS4(x) DIMS4(y) DIMS4(z) DIMS4(w)
        }
        c += __shfl_xor(c, 1, 64);
        c += __shfl_xor(c, 2, 64);
        if (sub == 0 && e < n_edges) {
            const float ex = __expf(c);
            atomicAdd(&denom[vi], ex);
            const int pos = offs[vj] + atomicAdd(&cursor[vj], 1);
            rec[pos] = make_int2(vi, __float_as_int(ex));
        }
    }
}

// K2: in-place reciprocal of denom.
__global__ void __launch_bounds__(256)
k2_rcp(float* __restrict__ denom, int n) {
    const int i = blockIdx.x * 256 + threadIdx.x;
    if (i < n) {
        const float d = denom[i];
        denom[i] = (d > 0.f) ? 1.f / d : 0.f;
    }
}

// K3: one wave per destination node; lane d owns dim d. No atomics.
__global__ void __launch_bounds__(256)
k3_gather(const int2* __restrict__ rec,
          const float* __restrict__ rdenom,
          const int* __restrict__ offs,
          const float* __restrict__ h,
          float* __restrict__ out, int n_nodes) {
    const int lane = threadIdx.x & 63;
    const int n = blockIdx.x * (blockDim.x >> 6) + (threadIdx.x >> 6);
    if (n >= n_nodes) return;
    const int beg = offs[n], end = offs[n + 1];
    float acc = 0.f;
    int k = beg;
    for (; k + 2 <= end; k += 2) {
        const int2 r0 = rec[k];
        const int2 r1 = rec[k + 1];
        const float w0 = __int_as_float(r0.y) * rdenom[r0.x];
        const float w1 = __int_as_float(r1.y) * rdenom[r1.x];
        acc += w0 * h[(size_t)r0.x * NDIM + lane];
        acc += w1 * h[(size_t)r1.x * NDIM + lane];
    }
    if (k < end) {
        const int2 r = rec[k];
        acc += __int_as_float(r.y) * rdenom[r.x] * h[(size_t)r.x * NDIM + lane];
    }
    out[(size_t)n * NDIM + lane] = acc;
}

extern "C" void kernel_launch(void* const* d_in, const int* in_sizes, int n_in,
                              void* d_out, int out_size, void* d_ws, size_t ws_size,
                              hipStream_t stream) {
    const float* h   = (const float*)d_in[0];
    const float* pw  = (const float*)d_in[1];
    const float* nw  = (const float*)d_in[2];
    const int* edges = (const int*)d_in[3];
    float* out = (float*)d_out;

    const int n_nodes = in_sizes[0] / NDIM;
    const int n_edges = in_sizes[3] / 8;
    const size_t E = (size_t)n_edges, N = (size_t)n_nodes;

    char* p = (char*)d_ws;
    int2*  rec    = (int2*)p;  p += E * 8;
    int*   offs   = (int*)p;   p += (N + 1) * 4;  // doubles as hist
    int*   cursor = (int*)p;   p += N * 4;
    float* denom  = (float*)p; p += N * 4;        // becomes rdenom
    int*   bsum   = (int*)p;   p += 1024;

    hipMemsetAsync(offs,   0, (N + 1) * 4, stream);
    hipMemsetAsync(cursor, 0, N * 4, stream);
    hipMemsetAsync(denom,  0, N * 4, stream);

    k0_hist<<<(n_edges + 255) / 256, 256, 0, stream>>>(edges, offs, n_edges);

    const int nb = (n_nodes + 255) / 256;  // 196 <= 256
    scan_blocks<<<nb, 256, 0, stream>>>(offs, bsum, n_nodes);
    scan_top<<<1, 256, 0, stream>>>(bsum, nb);
    scan_add<<<(n_nodes + 1 + 255) / 256, 256, 0, stream>>>(offs, bsum, n_nodes, n_edges);

    k1_logits<<<2048, 256, 0, stream>>>(edges, h, pw, nw, offs, cursor, denom, rec, n_edges);

    k2_rcp<<<(n_nodes + 255) / 256, 256, 0, stream>>>(denom, n_nodes);

    k3_gather<<<(n_nodes + 3) / 4, 256, 0, stream>>>(rec, denom, offs, h, out, n_nodes);
}

// Round 4
// 499.962 us; speedup vs baseline: 1.0209x; 1.0209x over previous
//
#include <hip/hip_runtime.h>
#include <math.h>

#define NDIM 64

#define DIMS4(COMP)                                                          \
    { const float pa = fmaxf(a.COMP, 0.f), na = fmaxf(-a.COMP, 0.f);         \
      const float pb = fmaxf(b.COMP, 0.f), nb = fmaxf(-b.COMP, 0.f);         \
      c += pa * W0[q].COMP + pb * W1[q].COMP + pa * pb * W2[q].COMP          \
         - na * W3[q].COMP - nb * W4[q].COMP - na * nb * W5[q].COMP; }

// K1: 4 lanes per edge, 16 edges per wave tile.
// Writes ex[e] = exp(logit); fire-and-forget atomics for denom[vi], hist[vj].
// No return-value atomics, no random stores -> latency off the critical path.
__global__ void __launch_bounds__(256)
k1_logits(const int* __restrict__ edges,
          const float* __restrict__ h,
          const float* __restrict__ pw,
          const float* __restrict__ nw,
          float* __restrict__ ex,
          float* __restrict__ denom,
          int* __restrict__ hist,
          int n_edges) {
    const int lane = threadIdx.x & 63;
    const int sub  = lane & 3;        // 16-dim slice
    const int grp  = lane >> 2;       // edge within 16-edge tile
    const int wid  = blockIdx.x * (blockDim.x >> 6) + (threadIdx.x >> 6);
    const int nwaves = gridDim.x * (blockDim.x >> 6);

    const float4* pw4 = (const float4*)pw;
    const float4* nw4 = (const float4*)nw;
    float4 W0[4], W1[4], W2[4], W3[4], W4[4], W5[4];
    #pragma unroll
    for (int q = 0; q < 4; ++q) {
        W0[q] = pw4[     sub * 4 + q];
        W1[q] = pw4[16 + sub * 4 + q];
        W2[q] = pw4[32 + sub * 4 + q];
        W3[q] = nw4[     sub * 4 + q];
        W4[q] = nw4[16 + sub * 4 + q];
        W5[q] = nw4[32 + sub * 4 + q];
    }

    const int ntiles = (n_edges + 15) >> 4;
    for (int t = wid; t < ntiles; t += nwaves) {
        const int e  = t * 16 + grp;
        const int ee = min(e, n_edges - 1);
        const int vi = edges[ee * 8 + 1];
        const int vj = edges[ee * 8 + 2];
        const float4* hi4 = (const float4*)(h + (size_t)vi * NDIM + sub * 16);
        const float4* hj4 = (const float4*)(h + (size_t)vj * NDIM + sub * 16);
        float c = 0.f;
        #pragma unroll
        for (int q = 0; q < 4; ++q) {
            const float4 a = hi4[q];
            const float4 b = hj4[q];
            DIMS4(x) DIMS4(y) DIMS4(z) DIMS4(w)
        }
        c += __shfl_xor(c, 1, 64);
        c += __shfl_xor(c, 2, 64);
        if (sub == 0 && e < n_edges) {
            const float x = __expf(c);
            ex[e] = x;
            atomicAdd(&denom[vi], x);   // fire-and-forget
            atomicAdd(&hist[vj], 1);    // fire-and-forget
        }
    }
}

// ---- exclusive scan over hist (n <= 256*256 entries) ----
__global__ void __launch_bounds__(256)
scan_blocks(int* __restrict__ data, int* __restrict__ bsum, int n) {
    __shared__ int sm[256];
    const int t = threadIdx.x;
    const int i = blockIdx.x * 256 + t;
    int v = (i < n) ? data[i] : 0;
    sm[t] = v;
    __syncthreads();
    int x = v;
    #pragma unroll
    for (int off = 1; off < 256; off <<= 1) {
        int add = (t >= off) ? sm[t - off] : 0;
        __syncthreads();
        x += add; sm[t] = x;
        __syncthreads();
    }
    if (i < n) data[i] = x - v;
    if (t == 255) bsum[blockIdx.x] = x;
}

__global__ void __launch_bounds__(256)
scan_top(int* __restrict__ bsum, int nb) {
    __shared__ int sm[256];
    const int t = threadIdx.x;
    int v = (t < nb) ? bsum[t] : 0;
    sm[t] = v;
    __syncthreads();
    int x = v;
    #pragma unroll
    for (int off = 1; off < 256; off <<= 1) {
        int add = (t >= off) ? sm[t - off] : 0;
        __syncthreads();
        x += add; sm[t] = x;
        __syncthreads();
    }
    if (t < nb) bsum[t] = x - v;
}

__global__ void __launch_bounds__(256)
scan_add(int* __restrict__ data, const int* __restrict__ bsum, int n, int total) {
    const int i = blockIdx.x * 256 + threadIdx.x;
    if (i < n) data[i] += bsum[blockIdx.x];
    else if (i == n) data[i] = total;
}

// K2: in-place reciprocal of denom.
__global__ void __launch_bounds__(256)
k2_rcp(float* __restrict__ denom, int n) {
    const int i = blockIdx.x * 256 + threadIdx.x;
    if (i < n) {
        const float d = denom[i];
        denom[i] = (d > 0.f) ? 1.f / d : 0.f;
    }
}

// K3a: thread per edge. Cursor atomic + random 8B store, hidden by TLP
// across 1.6M independent threads. Folds rdenom so rec = (vi, attn).
__global__ void __launch_bounds__(256)
k3a_scatter(const int* __restrict__ edges,
            const float* __restrict__ ex,
            const float* __restrict__ rdenom,
            const int* __restrict__ offs,
            int* __restrict__ cursor,
            int2* __restrict__ rec,
            int n_edges) {
    const int e = blockIdx.x * 256 + threadIdx.x;
    if (e >= n_edges) return;
    const int vi = edges[e * 8 + 1];
    const int vj = edges[e * 8 + 2];
    const float attn = ex[e] * rdenom[vi];
    const int pos = offs[vj] + atomicAdd(&cursor[vj], 1);
    rec[pos] = make_int2(vi, __float_as_int(attn));
}

// K3b: one wave per destination node; lane d owns dim d. No atomics.
__global__ void __launch_bounds__(256)
k3b_gather(const int2* __restrict__ rec,
           const int* __restrict__ offs,
           const float* __restrict__ h,
           float* __restrict__ out, int n_nodes) {
    const int lane = threadIdx.x & 63;
    const int n = blockIdx.x * (blockDim.x >> 6) + (threadIdx.x >> 6);
    if (n >= n_nodes) return;
    const int beg = offs[n], end = offs[n + 1];
    float acc = 0.f;
    int k = beg;
    for (; k + 2 <= end; k += 2) {
        const int2 r0 = rec[k];
        const int2 r1 = rec[k + 1];
        acc += __int_as_float(r0.y) * h[(size_t)r0.x * NDIM + lane];
        acc += __int_as_float(r1.y) * h[(size_t)r1.x * NDIM + lane];
    }
    if (k < end) {
        const int2 r = rec[k];
        acc += __int_as_float(r.y) * h[(size_t)r.x * NDIM + lane];
    }
    out[(size_t)n * NDIM + lane] = acc;
}

extern "C" void kernel_launch(void* const* d_in, const int* in_sizes, int n_in,
                              void* d_out, int out_size, void* d_ws, size_t ws_size,
                              hipStream_t stream) {
    const float* h   = (const float*)d_in[0];
    const float* pw  = (const float*)d_in[1];
    const float* nw  = (const float*)d_in[2];
    const int* edges = (const int*)d_in[3];
    float* out = (float*)d_out;

    const int n_nodes = in_sizes[0] / NDIM;
    const int n_edges = in_sizes[3] / 8;
    const size_t E = (size_t)n_edges, N = (size_t)n_nodes;

    // ws layout (~19.8 MB; R1 proved >=19.6 MB available):
    char* p = (char*)d_ws;
    float* ex     = (float*)p; p += E * 4;
    int2*  rec    = (int2*)p;  p += E * 8;
    int*   offs   = (int*)p;   p += (N + 1) * 4;  // doubles as hist
    int*   cursor = (int*)p;   p += N * 4;
    float* denom  = (float*)p; p += N * 4;        // becomes rdenom
    int*   bsum   = (int*)p;   p += 1024;

    // offs, cursor, denom are contiguous -> single memset
    hipMemsetAsync(offs, 0, (3 * N + 1) * 4, stream);

    k1_logits<<<2048, 256, 0, stream>>>(edges, h, pw, nw, ex, denom, offs, n_edges);

    const int nb = (n_nodes + 255) / 256;   // 196 <= 256
    scan_blocks<<<nb, 256, 0, stream>>>(offs, bsum, n_nodes);
    scan_top<<<1, 256, 0, stream>>>(bsum, nb);
    scan_add<<<(n_nodes + 1 + 255) / 256, 256, 0, stream>>>(offs, bsum, n_nodes, n_edges);

    k2_rcp<<<(n_nodes + 255) / 256, 256, 0, stream>>>(denom, n_nodes);

    k3a_scatter<<<(n_edges + 255) / 256, 256, 0, stream>>>(edges, ex, denom, offs, cursor, rec, n_edges);

    k3b_gather<<<(n_nodes + 3) / 4, 256, 0, stream>>>(rec, offs, h, out, n_nodes);
}

// Round 5
// 309.591 us; speedup vs baseline: 1.6487x; 1.6149x over previous
//
#include <hip/hip_runtime.h>
#include <math.h>

#define NDIM 64

// ---------- K00: h (f32) -> h16 (bf16 RNE), 4 elems/thread ----------
__global__ void __launch_bounds__(256)
k00_cvt(const float* __restrict__ h, unsigned int* __restrict__ h16, int n4) {
    const int i = blockIdx.x * 256 + threadIdx.x;   // index of float4
    if (i >= n4) return;
    const float4 f = ((const float4*)h)[i];
    unsigned int ux = __float_as_uint(f.x), uy = __float_as_uint(f.y);
    unsigned int uz = __float_as_uint(f.z), uw = __float_as_uint(f.w);
    unsigned int bx = (ux + 0x7fffu + ((ux >> 16) & 1u)) >> 16;
    unsigned int by = (uy + 0x7fffu + ((uy >> 16) & 1u)) >> 16;
    unsigned int bz = (uz + 0x7fffu + ((uz >> 16) & 1u)) >> 16;
    unsigned int bw = (uw + 0x7fffu + ((uw >> 16) & 1u)) >> 16;
    ((uint2*)h16)[i] = make_uint2(bx | (by << 16), bz | (bw << 16));
}

__device__ __forceinline__ float edge_term(float a, float b,
                                           float w0, float w1, float w2,
                                           float w3, float w4, float w5) {
    const float pa = fmaxf(a, 0.f), na = pa - a;   // na = max(-a,0)
    const float pb = fmaxf(b, 0.f), nb = pb - b;
    return pa * w0 + pb * w1 + (pa * pb) * w2
         - (na * w3 + nb * w4 + (na * nb) * w5);
}

// ---------- K1: thread per edge; weights wave-uniform (SGPR) ----------
template <bool BF16>
__global__ void __launch_bounds__(256)
k1_logits(const int* __restrict__ edges,
          const void* __restrict__ hptr,
          const float* __restrict__ pw,
          const float* __restrict__ nw,
          float* __restrict__ ex,
          int* __restrict__ hist,
          int n_edges) {
    const int e = blockIdx.x * 256 + threadIdx.x;
    if (e >= n_edges) return;
    const int vi = edges[e * 8 + 1];
    const int vj = edges[e * 8 + 2];

    float c = 0.f;
    if (BF16) {
        const unsigned short* h16 = (const unsigned short*)hptr;
        const uint4* hi = (const uint4*)(h16 + (size_t)vi * NDIM);
        const uint4* hj = (const uint4*)(h16 + (size_t)vj * NDIM);
        #pragma unroll 4
        for (int q = 0; q < 8; ++q) {           // 8 dims per chunk
            const uint4 ua = hi[q];
            const uint4 ub = hj[q];
            const unsigned int au[4] = {ua.x, ua.y, ua.z, ua.w};
            const unsigned int bu[4] = {ub.x, ub.y, ub.z, ub.w};
            #pragma unroll
            for (int k = 0; k < 4; ++k) {
                const int d = q * 8 + k * 2;
                const float a0 = __uint_as_float(au[k] << 16);
                const float a1 = __uint_as_float(au[k] & 0xffff0000u);
                const float b0 = __uint_as_float(bu[k] << 16);
                const float b1 = __uint_as_float(bu[k] & 0xffff0000u);
                c += edge_term(a0, b0, pw[d], pw[64 + d], pw[128 + d],
                                       nw[d], nw[64 + d], nw[128 + d]);
                c += edge_term(a1, b1, pw[d + 1], pw[64 + d + 1], pw[128 + d + 1],
                                       nw[d + 1], nw[64 + d + 1], nw[128 + d + 1]);
            }
        }
    } else {
        const float* h = (const float*)hptr;
        const float4* hi = (const float4*)(h + (size_t)vi * NDIM);
        const float4* hj = (const float4*)(h + (size_t)vj * NDIM);
        #pragma unroll 4
        for (int q = 0; q < 16; ++q) {          // 4 dims per chunk
            const float4 a = hi[q];
            const float4 b = hj[q];
            const int d = q * 4;
            c += edge_term(a.x, b.x, pw[d],     pw[64 + d],     pw[128 + d],
                                     nw[d],     nw[64 + d],     nw[128 + d]);
            c += edge_term(a.y, b.y, pw[d + 1], pw[64 + d + 1], pw[128 + d + 1],
                                     nw[d + 1], nw[64 + d + 1], nw[128 + d + 1]);
            c += edge_term(a.z, b.z, pw[d + 2], pw[64 + d + 2], pw[128 + d + 2],
                                     nw[d + 2], nw[64 + d + 2], nw[128 + d + 2]);
            c += edge_term(a.w, b.w, pw[d + 3], pw[64 + d + 3], pw[128 + d + 3],
                                     nw[d + 3], nw[64 + d + 3], nw[128 + d + 3]);
        }
    }
    ex[e] = __expf(c);
    atomicAdd(&hist[vj], 1);        // fire-and-forget
}

// ---------- K2: thread per node; binary search on sorted vi; rdenom ----------
__global__ void __launch_bounds__(256)
k2_denom(const int* __restrict__ edges,
         const float* __restrict__ ex,
         float* __restrict__ rdenom,
         int n_edges, int n_nodes) {
    const int n = blockIdx.x * 256 + threadIdx.x;
    if (n >= n_nodes) return;
    int lo = 0, hi = n_edges;
    while (lo < hi) { int mid = (lo + hi) >> 1; if (edges[(size_t)mid * 8 + 1] < n) lo = mid + 1; else hi = mid; }
    const int beg = lo;
    hi = n_edges;
    while (lo < hi) { int mid = (lo + hi) >> 1; if (edges[(size_t)mid * 8 + 1] < n + 1) lo = mid + 1; else hi = mid; }
    const int end = lo;
    float s = 0.f;
    for (int e = beg; e < end; ++e) s += ex[e];
    rdenom[n] = (end > beg) ? 1.f / s : 0.f;
}

// ---------- exclusive scan over hist (n <= 256*256) ----------
__global__ void __launch_bounds__(256)
scan_blocks(int* __restrict__ data, int* __restrict__ bsum, int n) {
    __shared__ int sm[256];
    const int t = threadIdx.x;
    const int i = blockIdx.x * 256 + t;
    int v = (i < n) ? data[i] : 0;
    sm[t] = v;
    __syncthreads();
    int x = v;
    #pragma unroll
    for (int off = 1; off < 256; off <<= 1) {
        int add = (t >= off) ? sm[t - off] : 0;
        __syncthreads();
        x += add; sm[t] = x;
        __syncthreads();
    }
    if (i < n) data[i] = x - v;
    if (t == 255) bsum[blockIdx.x] = x;
}

__global__ void __launch_bounds__(256)
scan_top(int* __restrict__ bsum, int nb) {
    __shared__ int sm[256];
    const int t = threadIdx.x;
    int v = (t < nb) ? bsum[t] : 0;
    sm[t] = v;
    __syncthreads();
    int x = v;
    #pragma unroll
    for (int off = 1; off < 256; off <<= 1) {
        int add = (t >= off) ? sm[t - off] : 0;
        __syncthreads();
        x += add; sm[t] = x;
        __syncthreads();
    }
    if (t < nb) bsum[t] = x - v;
}

__global__ void __launch_bounds__(256)
scan_add(int* __restrict__ data, const int* __restrict__ bsum, int n, int total) {
    const int i = blockIdx.x * 256 + threadIdx.x;
    if (i < n) data[i] += bsum[blockIdx.x];
    else if (i == n) data[i] = total;
}

// ---------- K3a: thread per edge; cursor atomic hidden by TLP ----------
__global__ void __launch_bounds__(256)
k3a_scatter(const int* __restrict__ edges,
            const float* __restrict__ ex,
            const float* __restrict__ rdenom,
            const int* __restrict__ offs,
            int* __restrict__ cursor,
            int2* __restrict__ rec,
            int n_edges) {
    const int e = blockIdx.x * 256 + threadIdx.x;
    if (e >= n_edges) return;
    const int vi = edges[e * 8 + 1];
    const int vj = edges[e * 8 + 2];
    const float attn = ex[e] * rdenom[vi];
    const int pos = offs[vj] + atomicAdd(&cursor[vj], 1);
    rec[pos] = make_int2(vi, __float_as_int(attn));
}

// ---------- K3b: wave per destination node; lane = dim; no atomics ----------
template <bool BF16>
__global__ void __launch_bounds__(256)
k3b_gather(const int2* __restrict__ rec,
           const int* __restrict__ offs,
           const void* __restrict__ hptr,
           float* __restrict__ out, int n_nodes) {
    const int lane = threadIdx.x & 63;
    const int n = blockIdx.x * (blockDim.x >> 6) + (threadIdx.x >> 6);
    if (n >= n_nodes) return;
    const int beg = offs[n], end = offs[n + 1];
    float acc = 0.f;
    int k = beg;
    if (BF16) {
        const unsigned short* h16 = (const unsigned short*)hptr;
        for (; k + 2 <= end; k += 2) {
            const int2 r0 = rec[k];
            const int2 r1 = rec[k + 1];
            const float h0 = __uint_as_float(((unsigned int)h16[(size_t)r0.x * NDIM + lane]) << 16);
            const float h1 = __uint_as_float(((unsigned int)h16[(size_t)r1.x * NDIM + lane]) << 16);
            acc += __int_as_float(r0.y) * h0;
            acc += __int_as_float(r1.y) * h1;
        }
        if (k < end) {
            const int2 r = rec[k];
            acc += __int_as_float(r.y) *
                   __uint_as_float(((unsigned int)h16[(size_t)r.x * NDIM + lane]) << 16);
        }
    } else {
        const float* h = (const float*)hptr;
        for (; k + 2 <= end; k += 2) {
            const int2 r0 = rec[k];
            const int2 r1 = rec[k + 1];
            acc += __int_as_float(r0.y) * h[(size_t)r0.x * NDIM + lane];
            acc += __int_as_float(r1.y) * h[(size_t)r1.x * NDIM + lane];
        }
        if (k < end) {
            const int2 r = rec[k];
            acc += __int_as_float(r.y) * h[(size_t)r.x * NDIM + lane];
        }
    }
    out[(size_t)n * NDIM + lane] = acc;
}

extern "C" void kernel_launch(void* const* d_in, const int* in_sizes, int n_in,
                              void* d_out, int out_size, void* d_ws, size_t ws_size,
                              hipStream_t stream) {
    const float* h   = (const float*)d_in[0];
    const float* pw  = (const float*)d_in[1];
    const float* nw  = (const float*)d_in[2];
    const int* edges = (const int*)d_in[3];
    float* out = (float*)d_out;

    const int n_nodes = in_sizes[0] / NDIM;
    const int n_edges = in_sizes[3] / 8;
    const size_t E = (size_t)n_edges, N = (size_t)n_nodes;

    // full layout needs ex(E*4) + rec(E*8) + h16(N*128) + offs/cursor/rdenom/bsum
    const size_t node_bytes = (N + 1) * 4 + N * 4 + N * 4 + 1024;
    const size_t need_full  = E * 4 + E * 8 + N * NDIM * 2 + node_bytes;
    const bool full = ws_size >= need_full;

    char* p = (char*)d_ws;
    float* ex   = (float*)p; p += E * 4;
    int2*  rec  = (int2*)p;  p += E * 8;
    unsigned int* h16 = nullptr;
    if (full) { h16 = (unsigned int*)p; p += N * NDIM * 2; }
    int*   offs   = (int*)p;   p += (N + 1) * 4;   // doubles as hist
    int*   cursor = (int*)p;   p += N * 4;
    float* rdenom = (float*)p; p += N * 4;
    int*   bsum   = (int*)p;   p += 1024;

    // offs and cursor contiguous -> one memset
    hipMemsetAsync(offs, 0, (2 * N + 1) * 4, stream);

    const void* hh = full ? (const void*)h16 : (const void*)h;
    if (full) {
        const int n4 = (int)(N * NDIM / 4);
        k00_cvt<<<(n4 + 255) / 256, 256, 0, stream>>>(h, h16, n4);
        k1_logits<true><<<(n_edges + 255) / 256, 256, 0, stream>>>(edges, hh, pw, nw, ex, offs, n_edges);
    } else {
        k1_logits<false><<<(n_edges + 255) / 256, 256, 0, stream>>>(edges, hh, pw, nw, ex, offs, n_edges);
    }

    k2_denom<<<(n_nodes + 255) / 256, 256, 0, stream>>>(edges, ex, rdenom, n_edges, n_nodes);

    const int nb = (n_nodes + 255) / 256;   // 196 <= 256
    scan_blocks<<<nb, 256, 0, stream>>>(offs, bsum, n_nodes);
    scan_top<<<1, 256, 0, stream>>>(bsum, nb);
    scan_add<<<(n_nodes + 1 + 255) / 256, 256, 0, stream>>>(offs, bsum, n_nodes, n_edges);

    k3a_scatter<<<(n_edges + 255) / 256, 256, 0, stream>>>(edges, ex, rdenom, offs, cursor, rec, n_edges);

    if (full) k3b_gather<true ><<<(n_nodes + 3) / 4, 256, 0, stream>>>(rec, offs, hh, out, n_nodes);
    else      k3b_gather<false><<<(n_nodes + 3) / 4, 256, 0, stream>>>(rec, offs, hh, out, n_nodes);
}